// Round 3
// baseline (5249.728 us; speedup 1.0000x reference)
//
#include <hip/hip_runtime.h>
#include <cstdint>
#include <cstddef>

// ---------------------------------------------------------------------------
// 2-layer GRU imputation RNN, B=256, T=256, D_IN=128, D_H=512.
// R4: R3 structure (2-phase step, layer-0 fused in-WG, fg-major XCD weight
// locality) + latency fixes:
//  * staging loads: inline-asm global_load_dwordx4 sc0 sc1, 2 in flight,
//    ONE vmcnt(0) (R3's __hip_atomic_load u64 serialized 4 MALL round trips
//    per thread per phase ~ 7-8 us/step of pure latency).
//  * exchange stores widened: bf16 h/h1 -> LDS tile -> 64x 16B sc0 sc1 wide
//    stores (was 512x 2B write-through stores per WG).
//  * hsc/hfin widened via fp32 LDS (stride 36 for 16B alignment).
//  * biases/B-pointers hoisted out of the t-loop.
// ---------------------------------------------------------------------------

#define BB  256
#define TT  256
#define DIN 128
#define DH  512

typedef __attribute__((ext_vector_type(8))) short short8;   // 8 x bf16
typedef __attribute__((ext_vector_type(4))) float f32x4;
typedef __attribute__((ext_vector_type(4))) unsigned int u32x4;
typedef unsigned short u16;
typedef unsigned long long u64;

// ws layout (float units)
#define OFF_BAR   0                               // [16] group counters, 64B apart
#define OFF_HBF   256                             // [256][512] bf16 (carried h)
#define OFF_H1BF  (OFF_HBF + BB*DH/2)             // [256][512] bf16 (layer-0 out)
#define OFF_WOUT  (OFF_H1BF + BB*DH/2)            // bf16 weights below
#define OFF_WHH0  (OFF_WOUT + (DIN*DH)/2)
#define OFF_WIH0  (OFF_WHH0 + (3*DH*DH)/2)
#define OFF_WIH1  (OFF_WIH0 + (3*DH*DIN)/2)
#define OFF_WHH1  (OFF_WIH1 + (3*DH*DH)/2)
#define WS_FLOATS (OFF_WHH1 + (3*DH*DH)/2)

__device__ __forceinline__ float sigm(float x)   { return 1.0f / (1.0f + __expf(-x)); }
__device__ __forceinline__ float tanh_f(float x) { return 2.0f / (1.0f + __expf(-2.0f * x)) - 1.0f; }

__device__ __forceinline__ u16 f2bf(float x) {            // RNE f32->bf16
    unsigned u = __builtin_bit_cast(unsigned, x);
    u += 0x7fffu + ((u >> 16) & 1u);
    return (u16)(u >> 16);
}

// ---- MALL-coherent staged accesses (bypass L1+L2, XCD-agnostic) ------------
// Non-atomic wide loads/stores with sc0 sc1: same coherence point (MALL) as
// R2/R3's atomics, but pipelineable (compiler can't serialize them).
__device__ __forceinline__ u32x4 ld_b128_sc(const void* p) {
    u32x4 r;
    asm volatile("global_load_dwordx4 %0, %1, off sc0 sc1" : "=v"(r) : "v"(p));
    return r;
}
__device__ __forceinline__ void st_b128_sc(void* p, u32x4 v) {
    asm volatile("global_store_dwordx4 %0, %1, off sc0 sc1" :: "v"(p), "v"(v) : "memory");
}

// 16-WG group barrier. Release: each wave drains its own stores (write-through,
// so vmcnt(0) == visible at MALL). Acquire: consumers read with sc1.
__device__ __forceinline__ void group_bar(unsigned* bar, unsigned target) {
    asm volatile("s_waitcnt vmcnt(0)" ::: "memory");
    __syncthreads();
    if (threadIdx.x == 0) {
        __hip_atomic_fetch_add(bar, 1u, __ATOMIC_RELAXED, __HIP_MEMORY_SCOPE_AGENT);
        while (__hip_atomic_load(bar, __ATOMIC_RELAXED, __HIP_MEMORY_SCOPE_AGENT) < target) {
            __builtin_amdgcn_s_sleep(1);
        }
    }
    __syncthreads();
}

// fp32 -> bf16 weight conversion (runs once per call, before the RNN kernel)
__global__ void prep_kernel(const float* __restrict__ Wout, const float* __restrict__ Whh0,
                            const float* __restrict__ Wih0, const float* __restrict__ Wih1,
                            const float* __restrict__ Whh1, float* __restrict__ ws) {
    u16* dOut = (u16*)(ws + OFF_WOUT);
    u16* dHH0 = (u16*)(ws + OFF_WHH0);
    u16* dIH0 = (u16*)(ws + OFF_WIH0);
    u16* dIH1 = (u16*)(ws + OFF_WIH1);
    u16* dHH1 = (u16*)(ws + OFF_WHH1);
    const int N0 = DIN * DH, N1 = 3 * DH * DH, N2 = 3 * DH * DIN;
    const int total = N0 + 3 * N1 + N2;
    for (int i = blockIdx.x * 256 + threadIdx.x; i < total; i += gridDim.x * 256) {
        int j = i;
        if (j < N0) { dOut[j] = f2bf(Wout[j]); continue; } j -= N0;
        if (j < N1) { dHH0[j] = f2bf(Whh0[j]); continue; } j -= N1;
        if (j < N2) { dIH0[j] = f2bf(Wih0[j]); continue; } j -= N2;
        if (j < N1) { dIH1[j] = f2bf(Wih1[j]); continue; } j -= N1;
        dHH1[j] = f2bf(Whh1[j]);
    }
}

__global__ __launch_bounds__(512) void rnn_kernel(
    const float* __restrict__ X,    const float* __restrict__ Mm,
    const float* __restrict__ bih0, const float* __restrict__ bhh0,
    const float* __restrict__ bih1, const float* __restrict__ bhh1,
    const float* __restrict__ bout,
    float* __restrict__ out, float* __restrict__ ws)
{
    __shared__ __align__(16) u16 Atile[16 * 520];    // H / H1 A-tile (16x512, padded)
    __shared__ __align__(16) u16 IMPL[16 * 136];     // imputed A-tile (16x128, padded)
    __shared__ __align__(16) u16 Sbf[16][2][16];     // bf16 exchange staging tile
    __shared__ float ghL[3][2][16][17];              // gh gate preacts (own cols)
    __shared__ float cplane[2][3][256];              // phase-B combine exchange
    __shared__ __align__(16) float H32L[16][36];     // carried h fp32 (own cols)
    __shared__ __align__(16) float H132L[16][36];    // layer-0 out fp32 (own cols)

    u16*   Hbf  = (u16*)(ws + OFF_HBF);
    u16*   H1bf = (u16*)(ws + OFF_H1BF);
    const u16* WbOut = (const u16*)(ws + OFF_WOUT);
    const u16* WbHH0 = (const u16*)(ws + OFF_WHH0);
    const u16* WbIH0 = (const u16*)(ws + OFF_WIH0);
    const u16* WbIH1 = (const u16*)(ws + OFF_WIH1);
    const u16* WbHH1 = (const u16*)(ws + OFF_WHH1);

    float* pre  = out;                               // [B][T][DIN]
    float* outc = out + BB * TT * DIN;               // [B][T][DIN]
    float* hfin = out + 2 * BB * TT * DIN;           // [B][DH]
    float* hsc  = hfin + BB * DH;                    // [B][T][DH]

    const int tid  = threadIdx.x;
    const int lane = tid & 63;
    const int v    = tid >> 6;           // wave 0..7
    const int fg   = blockIdx.x & 15;    // feature group (XCD = fg%8 -> L2 weight locality)
    const int bb   = blockIdx.x >> 4;    // batch block (16 rows) == barrier group
    const int m_   = lane & 15;          // A-row / B-col / C-col index
    const int q    = lane >> 4;          // quad
    const int q8   = q * 8;
    const int rowB = bb * 16 + q * 4;    // C-row batch base (+r)
    const int lrow = q * 4;              // local row base (+r)

    unsigned* bar = (unsigned*)(ws + OFF_BAR) + bb * 16;   // 64B-spaced counter
    unsigned ep = 0;

    // zero carried-h LDS (t==0 initial state)
    for (int i = tid; i < 16 * 36; i += 512) ((float*)H32L)[i] = 0.f;

    // ---- hoisted per-thread constants (invariant over t) ----
    const int fE  = v * 16 + m_;                         // est col (replicated)
    const int g   = v >> 1, ft = v & 1;                  // GH0 tile (waves 0..5)
    const int fp  = g * DH + (fg + 16 * ft) * 16 + m_;   // GH0 col
    const u16* BwE = WbOut + (size_t)fE * DH;
    const u16* BwG = WbHH0 + (size_t)fp * DH;
    const float bo  = bout[fE];
    const float bhG = (v < 6) ? bhh0[fp] : 0.f;

    // layer-0 gate combine (waves 0..1)
    const int ffA = (fg + 16 * v) * 16 + m_;
    const u16* B0 = WbIH0 + (size_t)ffA * DIN;
    const u16* B1 = B0 + (size_t)DH * DIN;
    const u16* B2 = B1 + (size_t)DH * DIN;
    const float bi0 = (v < 2) ? bih0[ffA] : 0.f;
    const float bi1 = (v < 2) ? bih0[DH + ffA] : 0.f;
    const float bi2 = (v < 2) ? bih0[2 * DH + ffA] : 0.f;

    // phase-B assignments (waves 0..5)
    const int ft3 = (v < 3) ? 0 : 1;
    const int g3  = v - 3 * ft3;
    const int ffB0 = (fg + 16 * ft3) * 16;
    const int gf  = g3 * DH + ffB0 + m_;
    const u16* Bi = WbIH1 + (size_t)gf * DH;
    const u16* Bh = WbHH1 + (size_t)gf * DH;
    const float biB = (v < 6) ? bih1[gf] : 0.f;
    const float bhB = (v < 6) ? bhh1[gf] : 0.f;

    // staging chunk indices (16 KB tile, 512 thr x 2 x 16 B)
    const int sr_ = tid >> 6, sc_ = tid & 63;            // row 0..7, 16B-chunk 0..63

    for (int t = 0; t <= TT; ++t) {
        // ------------- phase A: est + GH0 + layer-0 gates + H1 -------------
        float xv[4], mv[4];
        if (t < TT) {                                // prefetch X/Mm (plain, cached)
            #pragma unroll
            for (int r = 0; r < 4; ++r) {
                const int xi = ((rowB + r) * TT + t) * DIN + fE;
                xv[r] = X[xi]; mv[r] = Mm[xi];
            }
        }
        {   // stage Hbf -> Atile: 2 wide MALL loads in flight, one wait
            const u16* src = Hbf + bb * 16 * DH;
            u32x4 d0 = ld_b128_sc(src + sr_ * DH + sc_ * 8);
            u32x4 d1 = ld_b128_sc(src + (sr_ + 8) * DH + sc_ * 8);
            asm volatile("s_waitcnt vmcnt(0)" ::: "memory");
            *(u32x4*)(Atile + sr_ * 520 + sc_ * 8) = d0;
            *(u32x4*)(Atile + (sr_ + 8) * 520 + sc_ * 8) = d1;
        }
        __syncthreads();

        f32x4 aE = {0.f, 0.f, 0.f, 0.f}, aG = aE;
        if (v < 6) {
            #pragma unroll 4
            for (int kb = 0; kb < DH; kb += 32) {
                short8 a = *(const short8*)(Atile + m_ * 520 + kb + q8);
                aE = __builtin_amdgcn_mfma_f32_16x16x32_bf16(a, *(const short8*)(BwE + kb + q8), aE, 0, 0, 0);
                aG = __builtin_amdgcn_mfma_f32_16x16x32_bf16(a, *(const short8*)(BwG + kb + q8), aG, 0, 0, 0);
            }
        } else {
            #pragma unroll 4
            for (int kb = 0; kb < DH; kb += 32) {
                short8 a = *(const short8*)(Atile + m_ * 520 + kb + q8);
                aE = __builtin_amdgcn_mfma_f32_16x16x32_bf16(a, *(const short8*)(BwE + kb + q8), aE, 0, 0, 0);
            }
        }

        if (t == TT) {                               // tail: only final est
            if (v == fg) {
                #pragma unroll
                for (int r = 0; r < 4; ++r)
                    outc[((rowB + r) * TT + TT - 1) * DIN + fE] = aE[r] + bo;
            }
            break;                                   // uniform exit
        }
        #pragma unroll
        for (int r = 0; r < 4; ++r) {
            const float est = aE[r] + bo;
            const float imp = mv[r] * xv[r] + (1.f - mv[r]) * est;
            IMPL[(lrow + r) * 136 + fE] = f2bf(imp);
            if (v == fg) {                           // 8 of 16 WGs store a 16-col slice
                const int xi = ((rowB + r) * TT + t) * DIN + fE;
                pre[xi] = est;
                if (t > 0) outc[xi - DIN] = imp;
            }
        }
        if (v < 6) {
            #pragma unroll
            for (int r = 0; r < 4; ++r) ghL[g][ft][lrow + r][m_] = aG[r] + bhG;
        }
        __syncthreads();

        if (v < 2) {                                 // layer-0 gates + combine
            f32x4 a0 = {0.f,0.f,0.f,0.f}, a1 = a0, a2 = a0;
            #pragma unroll
            for (int kb = 0; kb < DIN; kb += 32) {
                short8 a = *(const short8*)(IMPL + m_ * 136 + kb + q8);
                a0 = __builtin_amdgcn_mfma_f32_16x16x32_bf16(a, *(const short8*)(B0 + kb + q8), a0, 0, 0, 0);
                a1 = __builtin_amdgcn_mfma_f32_16x16x32_bf16(a, *(const short8*)(B1 + kb + q8), a1, 0, 0, 0);
                a2 = __builtin_amdgcn_mfma_f32_16x16x32_bf16(a, *(const short8*)(B2 + kb + q8), a2, 0, 0, 0);
            }
            const int lc = v * 16 + m_;
            #pragma unroll
            for (int r = 0; r < 4; ++r) {
                const float rr = sigm(a0[r] + bi0 + ghL[0][v][lrow + r][m_]);
                const float zz = sigm(a1[r] + bi1 + ghL[1][v][lrow + r][m_]);
                const float nn = tanh_f(a2[r] + bi2 + rr * ghL[2][v][lrow + r][m_]);
                const float hp = H32L[lrow + r][lc];
                const float h1 = (1.f - zz) * nn + zz * hp;
                H132L[lrow + r][lc] = h1;
                Sbf[lrow + r][v][m_] = f2bf(h1);
            }
        }
        __syncthreads();
        if (tid < 64) {                              // 64x 16B wide exchange stores
            const int row = tid >> 2, sl = (tid >> 1) & 1, hf = tid & 1;
            const int col = (fg + 16 * sl) * 16 + hf * 8;
            st_b128_sc(H1bf + (bb * 16 + row) * DH + col, *(const u32x4*)&Sbf[row][sl][hf * 8]);
        }
        group_bar(bar, (++ep) * 16);

        // ------------- phase B: layer-1 (A = H1, 16 x 512) -------------
        {
            const u16* src = H1bf + bb * 16 * DH;
            u32x4 d0 = ld_b128_sc(src + sr_ * DH + sc_ * 8);
            u32x4 d1 = ld_b128_sc(src + (sr_ + 8) * DH + sc_ * 8);
            asm volatile("s_waitcnt vmcnt(0)" ::: "memory");
            *(u32x4*)(Atile + sr_ * 520 + sc_ * 8) = d0;
            *(u32x4*)(Atile + (sr_ + 8) * 520 + sc_ * 8) = d1;
        }
        __syncthreads();

        float sr4[4];                                  // gate-r preact (g3==0 waves)
        if (v < 6) {
            f32x4 ai = {0.f,0.f,0.f,0.f}, ah = ai;
            #pragma unroll 4
            for (int kb = 0; kb < DH; kb += 32) {
                short8 a = *(const short8*)(Atile + m_ * 520 + kb + q8);
                ai = __builtin_amdgcn_mfma_f32_16x16x32_bf16(a, *(const short8*)(Bi + kb + q8), ai, 0, 0, 0);
                ah = __builtin_amdgcn_mfma_f32_16x16x32_bf16(a, *(const short8*)(Bh + kb + q8), ah, 0, 0, 0);
            }
            if (g3 == 0) {
                #pragma unroll
                for (int r = 0; r < 4; ++r) sr4[r] = ai[r] + ah[r] + biB + bhB;
            } else if (g3 == 1) {
                #pragma unroll
                for (int r = 0; r < 4; ++r) cplane[ft3][0][m_ * 16 + q * 4 + r] = ai[r] + ah[r] + biB + bhB;
            } else {
                #pragma unroll
                for (int r = 0; r < 4; ++r) {
                    cplane[ft3][1][m_ * 16 + q * 4 + r] = ai[r] + biB;   // in_
                    cplane[ft3][2][m_ * 16 + q * 4 + r] = ah[r] + bhB;   // hn
                }
            }
        }
        __syncthreads();
        if (v == 0 || v == 3) {
            const int lc = ft3 * 16 + m_;
            #pragma unroll
            for (int r = 0; r < 4; ++r) {
                const int idx = m_ * 16 + q * 4 + r;
                const float rr = sigm(sr4[r]);
                const float zz = sigm(cplane[ft3][0][idx]);
                const float nn = tanh_f(cplane[ft3][1][idx] + rr * cplane[ft3][2][idx]);
                const float h1 = H132L[lrow + r][lc];
                const float hn = (1.f - zz) * nn + zz * h1;
                H32L[lrow + r][lc] = hn;
                Sbf[lrow + r][ft3][m_] = f2bf(hn);
            }
        }
        __syncthreads();
        if (tid < 64) {                              // wide exchange stores (h)
            const int row = tid >> 2, sl = (tid >> 1) & 1, hf = tid & 1;
            const int col = (fg + 16 * sl) * 16 + hf * 8;
            st_b128_sc(Hbf + (bb * 16 + row) * DH + col, *(const u32x4*)&Sbf[row][sl][hf * 8]);
        }
        if (tid < 128) {                             // wide hsc/hfin stores (plain)
            const int row = tid >> 3, sl = (tid >> 2) & 1, c4 = tid & 3;
            const int col = (fg + 16 * sl) * 16 + c4 * 4;
            const int b = bb * 16 + row;
            u32x4 val = *(const u32x4*)&H32L[row][sl * 16 + c4 * 4];
            *(u32x4*)(hsc + ((size_t)b * TT + t) * DH + col) = val;
            if (t == TT - 1) *(u32x4*)(hfin + (size_t)b * DH + col) = val;
        }
        group_bar(bar, (++ep) * 16);
    }
}

extern "C" void kernel_launch(void* const* d_in, const int* in_sizes, int n_in,
                              void* d_out, int out_size, void* d_ws, size_t ws_size,
                              hipStream_t stream) {
    const float* X    = (const float*)d_in[0];
    const float* Mm   = (const float*)d_in[1];
    const float* Wih0 = (const float*)d_in[2];
    const float* Whh0 = (const float*)d_in[3];
    const float* bih0 = (const float*)d_in[4];
    const float* bhh0 = (const float*)d_in[5];
    const float* Wih1 = (const float*)d_in[6];
    const float* Whh1 = (const float*)d_in[7];
    const float* bih1 = (const float*)d_in[8];
    const float* bhh1 = (const float*)d_in[9];
    const float* Wout = (const float*)d_in[10];
    const float* bout = (const float*)d_in[11];
    float* out = (float*)d_out;
    float* ws  = (float*)d_ws;

    // zero barrier counters + Hbf (initial hidden state)
    hipMemsetAsync(d_ws, 0, (size_t)(OFF_H1BF) * sizeof(float), stream);

    // weights fp32 -> bf16
    hipLaunchKernelGGL(prep_kernel, dim3(1024), dim3(256), 0, stream,
                       Wout, Whh0, Wih0, Wih1, Whh1, ws);

    // persistent RNN: 256 WGs (<= 256 CUs) x 512 threads, co-resident
    hipLaunchKernelGGL(rnn_kernel, dim3(256), dim3(512), 0, stream,
                       X, Mm, bih0, bhh0, bih1, bhh1, bout, out, ws);
}

// Round 6
// 4884.211 us; speedup vs baseline: 1.0748x; 1.0748x over previous
//
#include <hip/hip_runtime.h>
#include <cstdint>
#include <cstddef>

// ---------------------------------------------------------------------------
// 2-layer GRU imputation RNN, B=256, T=256, D_IN=128, D_H=512.
// R7 = R6 + correctness fix. R6's race: producer fg writes cols
// {16fg..16fg+16} u {256+16fg..+16} then raises flag fg, but gather16 treated
// flag p as certifying contiguous cols [32p,32p+32) -> slices published with
// only half their producers certified (stale halves, absmax 0.117).
// Fix: pair-gating. Pair j ready iff flags 2j AND 2j+1 >= gtag; that
// certifies slices j and j+8 exactly. Batch-stage all ready pairs with one
// vmcnt(0). Everything else identical to R6:
//  * per-producer seq flags at the MALL (sc0 sc1, 64B-spaced, monotone).
//  * wave 7 = gatherer stages ready slices into LDS, publishes LDS seq.
//  * waves 0-6 consume incrementally (one MFMA fragment per 32-col slice).
// ---------------------------------------------------------------------------

#define BB  256
#define TT  256
#define DIN 128
#define DH  512

typedef __attribute__((ext_vector_type(8))) short short8;   // 8 x bf16
typedef __attribute__((ext_vector_type(4))) float f32x4;
typedef __attribute__((ext_vector_type(4))) unsigned int u32x4;
typedef unsigned short u16;
typedef unsigned long long u64;

// ws layout (float units)
#define OFF_FLAGS 0                               // [2][16][16] flags, 64B apart
#define OFF_HBF   8192                            // [256][512] bf16 (carried h)
#define OFF_H1BF  (OFF_HBF + BB*DH/2)             // [256][512] bf16 (layer-0 out)
#define OFF_WOUT  (OFF_H1BF + BB*DH/2)            // bf16 weights below
#define OFF_WHH0  (OFF_WOUT + (DIN*DH)/2)
#define OFF_WIH0  (OFF_WHH0 + (3*DH*DH)/2)
#define OFF_WIH1  (OFF_WIH0 + (3*DH*DIN)/2)
#define OFF_WHH1  (OFF_WIH1 + (3*DH*DH)/2)
#define WS_FLOATS (OFF_WHH1 + (3*DH*DH)/2)

__device__ __forceinline__ float sigm(float x)   { return 1.0f / (1.0f + __expf(-x)); }
__device__ __forceinline__ float tanh_f(float x) { return 2.0f / (1.0f + __expf(-2.0f * x)) - 1.0f; }

__device__ __forceinline__ u16 f2bf(float x) {            // RNE f32->bf16
    unsigned u = __builtin_bit_cast(unsigned, x);
    u += 0x7fffu + ((u >> 16) & 1u);
    return (u16)(u >> 16);
}

// ---- MALL-coherent accesses (bypass L1+L2, XCD-agnostic; proven R2-R4) -----
__device__ __forceinline__ u32x4 ld_b128_sc(const void* p) {
    u32x4 r;
    asm volatile("global_load_dwordx4 %0, %1, off sc0 sc1" : "=v"(r) : "v"(p));
    return r;
}
__device__ __forceinline__ void st_b128_sc(void* p, u32x4 v) {
    asm volatile("global_store_dwordx4 %0, %1, off sc0 sc1" :: "v"(p), "v"(v) : "memory");
}
__device__ __forceinline__ unsigned ld_flag(const unsigned* p) {
    unsigned r;
    asm volatile("global_load_dword %0, %1, off sc0 sc1\n\ts_waitcnt vmcnt(0)"
                 : "=v"(r) : "v"(p) : "memory");
    return r;
}
__device__ __forceinline__ void st_flag(unsigned* p, unsigned v) {
    asm volatile("global_store_dword %0, %1, off sc0 sc1" :: "v"(p), "v"(v) : "memory");
}

// consumer-side LDS seq spin (lgkm-only: leaves vmem prefetches in flight)
__device__ __forceinline__ void spin_seq(unsigned* s, unsigned tag) {
    while (__hip_atomic_load(s, __ATOMIC_RELAXED, __HIP_MEMORY_SCOPE_WORKGROUP) < tag)
        __builtin_amdgcn_s_sleep(1);
    asm volatile("" ::: "memory");
}

// wave-7 gatherer, PAIR-GATED (R7 fix): pair j = producers {2j, 2j+1};
// their flags jointly certify slices j ([32j,32j+32)) and j+8 ([256+32j,...)).
__device__ __forceinline__ void gather16(const u16* src, u16* lbuf,
                                         const unsigned* F, unsigned gtag,
                                         unsigned* seq, unsigned stag, int lane) {
    const int p16 = lane & 15;
    const int row = lane >> 2, co = (lane & 3) * 8;       // 16 rows x 4 x 16B
    const unsigned* myflag = F + p16 * 16;                // 64B-spaced
    unsigned done = 0;                                    // 8 pair bits
    while (done != 0xFFu) {
        unsigned f = ld_flag(myflag);
        unsigned prod = (unsigned)__ballot(f >= gtag) & 0xFFFFu;
        unsigned prm  = prod & (prod >> 1) & 0x5555u;     // pair j ready at bit 2j
        unsigned want = 0;
        #pragma unroll
        for (int j = 0; j < 8; ++j) want |= ((prm >> (2 * j)) & 1u) << j;
        want &= ~done;
        if (want) {
            u32x4 d0[8], d1[8];                           // static-indexed only
            #pragma unroll
            for (int j = 0; j < 8; ++j) {
                if (want & (1u << j)) {
                    d0[j] = ld_b128_sc(src + (size_t)row * DH + j * 32 + co);
                    d1[j] = ld_b128_sc(src + (size_t)row * DH + 256 + j * 32 + co);
                }
            }
            asm volatile("s_waitcnt vmcnt(0)" ::: "memory");
            #pragma unroll
            for (int j = 0; j < 8; ++j) {
                if (want & (1u << j)) {
                    *(u32x4*)(lbuf + row * 520 + j * 32 + co) = d0[j];
                    *(u32x4*)(lbuf + row * 520 + 256 + j * 32 + co) = d1[j];
                }
            }
            asm volatile("s_waitcnt lgkmcnt(0)" ::: "memory");
            if (lane == 0) {
                #pragma unroll
                for (int j = 0; j < 8; ++j) {
                    if (want & (1u << j)) {
                        __hip_atomic_store(&seq[j], stag, __ATOMIC_RELAXED, __HIP_MEMORY_SCOPE_WORKGROUP);
                        __hip_atomic_store(&seq[j + 8], stag, __ATOMIC_RELAXED, __HIP_MEMORY_SCOPE_WORKGROUP);
                    }
                }
            }
            done |= want;
        }
        if (done != 0xFFu) __builtin_amdgcn_s_sleep(1);
    }
}

// fp32 -> bf16 weight conversion (runs once per call, before the RNN kernel)
__global__ void prep_kernel(const float* __restrict__ Wout, const float* __restrict__ Whh0,
                            const float* __restrict__ Wih0, const float* __restrict__ Wih1,
                            const float* __restrict__ Whh1, float* __restrict__ ws) {
    u16* dOut = (u16*)(ws + OFF_WOUT);
    u16* dHH0 = (u16*)(ws + OFF_WHH0);
    u16* dIH0 = (u16*)(ws + OFF_WIH0);
    u16* dIH1 = (u16*)(ws + OFF_WIH1);
    u16* dHH1 = (u16*)(ws + OFF_WHH1);
    const int N0 = DIN * DH, N1 = 3 * DH * DH, N2 = 3 * DH * DIN;
    const int total = N0 + 3 * N1 + N2;
    for (int i = blockIdx.x * 256 + threadIdx.x; i < total; i += gridDim.x * 256) {
        int j = i;
        if (j < N0) { dOut[j] = f2bf(Wout[j]); continue; } j -= N0;
        if (j < N1) { dHH0[j] = f2bf(Whh0[j]); continue; } j -= N1;
        if (j < N2) { dIH0[j] = f2bf(Wih0[j]); continue; } j -= N2;
        if (j < N1) { dIH1[j] = f2bf(Wih1[j]); continue; } j -= N1;
        dHH1[j] = f2bf(Whh1[j]);
    }
}

#define MFMA(A,B,C) __builtin_amdgcn_mfma_f32_16x16x32_bf16((A),(B),(C),0,0,0)

__global__ __launch_bounds__(512) void rnn_kernel(
    const float* __restrict__ X,    const float* __restrict__ Mm,
    const float* __restrict__ bih0, const float* __restrict__ bhh0,
    const float* __restrict__ bih1, const float* __restrict__ bhh1,
    const float* __restrict__ bout,
    float* __restrict__ out, float* __restrict__ ws)
{
    __shared__ __align__(16) u16 bufA[16 * 520];     // H tiles   (16x512, padded)
    __shared__ __align__(16) u16 bufB[16 * 520];     // H1 tiles  (16x512, padded)
    __shared__ __align__(16) u16 IMPL[16 * 136];     // imputed A-tile (16x128)
    __shared__ __align__(16) u16 Sbf[16][2][16];     // bf16 exchange staging tile
    __shared__ float ghL[3][2][16][17];              // gh gate preacts (own cols)
    __shared__ float cplane[2][3][256];              // phase-B combine exchange
    __shared__ __align__(16) float H32L[16][36];     // carried h fp32 (own cols)
    __shared__ __align__(16) float H132L[16][36];    // layer-0 out fp32 (own cols)
    __shared__ unsigned seqA[16], seqB[16];          // per-slice LDS ready tags

    u16*   Hbf  = (u16*)(ws + OFF_HBF);
    u16*   H1bf = (u16*)(ws + OFF_H1BF);
    const u16* WbOut = (const u16*)(ws + OFF_WOUT);
    const u16* WbHH0 = (const u16*)(ws + OFF_WHH0);
    const u16* WbIH0 = (const u16*)(ws + OFF_WIH0);
    const u16* WbIH1 = (const u16*)(ws + OFF_WIH1);
    const u16* WbHH1 = (const u16*)(ws + OFF_WHH1);

    float* pre  = out;                               // [B][T][DIN]
    float* outc = out + BB * TT * DIN;               // [B][T][DIN]
    float* hfin = out + 2 * BB * TT * DIN;           // [B][DH]
    float* hsc  = hfin + BB * DH;                    // [B][T][DH]

    const int tid  = threadIdx.x;
    const int lane = tid & 63;
    const int v    = tid >> 6;           // wave 0..7 (7 = gatherer)
    const int fg   = blockIdx.x & 15;    // feature group (weight L2 locality)
    const int bb   = blockIdx.x >> 4;    // batch block (16 rows) == flag group
    const int m_   = lane & 15;
    const int q    = lane >> 4;
    const int q8   = q * 8;
    const int rowB = bb * 16 + q * 4;
    const int lrow = q * 4;

    unsigned* FLG = (unsigned*)(ws + OFF_FLAGS);
    unsigned* F0  = FLG + ((0 * 16 + bb) * 16) * 16;   // H1bf flags (phase-A product)
    unsigned* F1  = FLG + ((1 * 16 + bb) * 16) * 16;   // Hbf  flags (phase-B product)
    unsigned* myF0 = F0 + fg * 16;
    unsigned* myF1 = F1 + fg * 16;

    // zero carried-h LDS + seq tags
    for (int i = tid; i < 16 * 36; i += 512) ((float*)H32L)[i] = 0.f;
    if (tid < 16) { seqA[tid] = 0u; seqB[tid] = 0u; }
    __syncthreads();

    // ---- hoisted per-thread constants ----
    const int fE   = v * 16 + m_;                        // est col (waves 0..6: tiles 0..6)
    const int fE2  = 112 + m_;                           // est tile 7 (wave 6)
    const int g    = v >> 1, ft = v & 1;                 // GH0 tile (waves 0..5)
    const int fp   = g * DH + (fg + 16 * ft) * 16 + m_;  // GH0 col
    const u16* BwE  = WbOut + (size_t)fE * DH;
    const u16* BwE2 = WbOut + (size_t)fE2 * DH;
    const u16* BwG  = WbHH0 + (size_t)fp * DH;
    const float bo  = (v < 7) ? bout[fE] : 0.f;
    const float bo2 = bout[fE2];
    const float bhG = (v < 6) ? bhh0[fp] : 0.f;

    const int ffA = (fg + 16 * v) * 16 + m_;             // layer-0 gate combine (waves 0..1)
    const u16* B0 = WbIH0 + (size_t)ffA * DIN;
    const u16* B1 = B0 + (size_t)DH * DIN;
    const u16* B2 = B1 + (size_t)DH * DIN;
    const float bi0 = (v < 2) ? bih0[ffA] : 0.f;
    const float bi1 = (v < 2) ? bih0[DH + ffA] : 0.f;
    const float bi2 = (v < 2) ? bih0[2 * DH + ffA] : 0.f;

    const int ft3 = (v < 3) ? 0 : 1;                     // phase-B (waves 0..5)
    const int g3  = v - 3 * ft3;
    const int gf  = g3 * DH + (fg + 16 * ft3) * 16 + m_;
    const u16* Bi = WbIH1 + (size_t)gf * DH;
    const u16* Bh = WbHH1 + (size_t)gf * DH;
    const float biB = (v < 6) ? bih1[gf] : 0.f;
    const float bhB = (v < 6) ? bhh1[gf] : 0.f;

    const u16* srcA = Hbf  + (size_t)bb * 16 * DH;
    const u16* srcB = H1bf + (size_t)bb * 16 * DH;

    for (int t = 0; t <= TT; ++t) {
        const unsigned stag = (unsigned)(t + 1);
        // ================= phase A: est + GH0 + layer-0 =================
        float xv[4], mv[4], xv2[4], mv2[4];
        if (v < 7 && t < TT) {                       // X/Mm prefetch (plain, cached)
            #pragma unroll
            for (int r = 0; r < 4; ++r) {
                const int xi = ((rowB + r) * TT + t) * DIN + fE;
                xv[r] = X[xi]; mv[r] = Mm[xi];
            }
            if (v == 6) {
                #pragma unroll
                for (int r = 0; r < 4; ++r) {
                    const int xi = ((rowB + r) * TT + t) * DIN + fE2;
                    xv2[r] = X[xi]; mv2[r] = Mm[xi];
                }
            }
        }

        f32x4 aE = {0.f,0.f,0.f,0.f}, aE2 = aE, aG = aE;
        if (v == 7) {
            gather16(srcA, bufA, F1, (unsigned)t, seqA, stag, lane);
        } else {
            // slice-incremental MFMA over K=512 (16 slices of 32)
            short8 wE = *(const short8*)(BwE + q8);
            short8 wE2, wG;
            if (v == 6) wE2 = *(const short8*)(BwE2 + q8);
            if (v < 6)  wG  = *(const short8*)(BwG + q8);
            for (int p = 0; p < 16; ++p) {
                spin_seq(&seqA[p], stag);
                short8 a = *(const short8*)(bufA + m_ * 520 + p * 32 + q8);
                short8 nE = wE, nE2 = wE2, nG = wG;
                if (p < 15) {
                    nE = *(const short8*)(BwE + (p + 1) * 32 + q8);
                    if (v == 6) nE2 = *(const short8*)(BwE2 + (p + 1) * 32 + q8);
                    if (v < 6)  nG  = *(const short8*)(BwG + (p + 1) * 32 + q8);
                }
                aE = MFMA(a, wE, aE);
                if (v == 6) aE2 = MFMA(a, wE2, aE2);
                if (v < 6)  aG  = MFMA(a, wG, aG);
                wE = nE; wE2 = nE2; wG = nG;
            }
        }

        if (t == TT) {                               // tail: only final est
            if (v == fg && v < 7) {
                #pragma unroll
                for (int r = 0; r < 4; ++r)
                    outc[((rowB + r) * TT + TT - 1) * DIN + fE] = aE[r] + bo;
            }
            if (v == 6 && fg == 7) {
                #pragma unroll
                for (int r = 0; r < 4; ++r)
                    outc[((rowB + r) * TT + TT - 1) * DIN + fE2] = aE2[r] + bo2;
            }
            break;                                   // uniform exit (all waves)
        }

        if (v < 7) {
            #pragma unroll
            for (int r = 0; r < 4; ++r) {
                const float est = aE[r] + bo;
                const float imp = mv[r] * xv[r] + (1.f - mv[r]) * est;
                IMPL[(lrow + r) * 136 + fE] = f2bf(imp);
                if (v == fg) {
                    const int xi = ((rowB + r) * TT + t) * DIN + fE;
                    pre[xi] = est;
                    if (t > 0) outc[xi - DIN] = imp;
                }
            }
            if (v == 6) {
                #pragma unroll
                for (int r = 0; r < 4; ++r) {
                    const float est = aE2[r] + bo2;
                    const float imp = mv2[r] * xv2[r] + (1.f - mv2[r]) * est;
                    IMPL[(lrow + r) * 136 + fE2] = f2bf(imp);
                    if (fg == 7) {
                        const int xi = ((rowB + r) * TT + t) * DIN + fE2;
                        pre[xi] = est;
                        if (t > 0) outc[xi - DIN] = imp;
                    }
                }
            }
            if (v < 6) {
                #pragma unroll
                for (int r = 0; r < 4; ++r) ghL[g][ft][lrow + r][m_] = aG[r] + bhG;
            }
        }
        __syncthreads();                             // sync1: IMPL + ghL ready

        if (v < 2) {                                 // layer-0 gates + combine
            f32x4 a0 = {0.f,0.f,0.f,0.f}, a1 = a0, a2 = a0;
            #pragma unroll
            for (int kb = 0; kb < DIN; kb += 32) {
                short8 a = *(const short8*)(IMPL + m_ * 136 + kb + q8);
                a0 = MFMA(a, *(const short8*)(B0 + kb + q8), a0);
                a1 = MFMA(a, *(const short8*)(B1 + kb + q8), a1);
                a2 = MFMA(a, *(const short8*)(B2 + kb + q8), a2);
            }
            const int lc = v * 16 + m_;
            #pragma unroll
            for (int r = 0; r < 4; ++r) {
                const float rr = sigm(a0[r] + bi0 + ghL[0][v][lrow + r][m_]);
                const float zz = sigm(a1[r] + bi1 + ghL[1][v][lrow + r][m_]);
                const float nn = tanh_f(a2[r] + bi2 + rr * ghL[2][v][lrow + r][m_]);
                const float hp = H32L[lrow + r][lc];
                const float h1 = (1.f - zz) * nn + zz * hp;
                H132L[lrow + r][lc] = h1;
                Sbf[lrow + r][v][m_] = f2bf(h1);
            }
        }
        __syncthreads();                             // sync2: Sbf(h1) ready
        if (tid < 64) {                              // wave 0: exchange store + flag
            const int row = tid >> 2, sl = (tid >> 1) & 1, hf = tid & 1;
            const int col = (fg + 16 * sl) * 16 + hf * 8;
            st_b128_sc(H1bf + (size_t)(bb * 16 + row) * DH + col,
                       *(const u32x4*)&Sbf[row][sl][hf * 8]);
            asm volatile("s_waitcnt vmcnt(0)" ::: "memory");
            if (tid == 0) st_flag(myF0, stag);
        }

        // ================= phase B: layer-1 =================
        float sr4[4];
        f32x4 ai = {0.f,0.f,0.f,0.f}, ah = ai;
        if (v == 7) {
            gather16(srcB, bufB, F0, stag, seqB, stag, lane);
        } else if (v < 6) {
            short8 wI = *(const short8*)(Bi + q8);
            short8 wH = *(const short8*)(Bh + q8);
            for (int p = 0; p < 16; ++p) {
                spin_seq(&seqB[p], stag);
                short8 a = *(const short8*)(bufB + m_ * 520 + p * 32 + q8);
                short8 nI = wI, nH = wH;
                if (p < 15) {
                    nI = *(const short8*)(Bi + (p + 1) * 32 + q8);
                    nH = *(const short8*)(Bh + (p + 1) * 32 + q8);
                }
                ai = MFMA(a, wI, ai);
                ah = MFMA(a, wH, ah);
                wI = nI; wH = nH;
            }
            if (g3 == 0) {
                #pragma unroll
                for (int r = 0; r < 4; ++r) sr4[r] = ai[r] + ah[r] + biB + bhB;
            } else if (g3 == 1) {
                #pragma unroll
                for (int r = 0; r < 4; ++r)
                    cplane[ft3][0][m_ * 16 + q * 4 + r] = ai[r] + ah[r] + biB + bhB;
            } else {
                #pragma unroll
                for (int r = 0; r < 4; ++r) {
                    cplane[ft3][1][m_ * 16 + q * 4 + r] = ai[r] + biB;   // in_
                    cplane[ft3][2][m_ * 16 + q * 4 + r] = ah[r] + bhB;   // hn
                }
            }
        }
        __syncthreads();                             // sync3: cplane ready
        if (v == 0 || v == 3) {
            const int lc = ft3 * 16 + m_;
            #pragma unroll
            for (int r = 0; r < 4; ++r) {
                const int idx = m_ * 16 + q * 4 + r;
                const float rr = sigm(sr4[r]);
                const float zz = sigm(cplane[ft3][0][idx]);
                const float nn = tanh_f(cplane[ft3][1][idx] + rr * cplane[ft3][2][idx]);
                const float h1 = H132L[lrow + r][lc];
                const float hn = (1.f - zz) * nn + zz * h1;
                H32L[lrow + r][lc] = hn;
                Sbf[lrow + r][ft3][m_] = f2bf(hn);
            }
        }
        __syncthreads();                             // sync4: Sbf(h) + H32L ready
        if (tid < 64) {                              // wave 0: exchange store + flag
            const int row = tid >> 2, sl = (tid >> 1) & 1, hf = tid & 1;
            const int col = (fg + 16 * sl) * 16 + hf * 8;
            st_b128_sc(Hbf + (size_t)(bb * 16 + row) * DH + col,
                       *(const u32x4*)&Sbf[row][sl][hf * 8]);
            asm volatile("s_waitcnt vmcnt(0)" ::: "memory");
            if (tid == 0) st_flag(myF1, stag);
        } else if (tid >= 128 && tid < 256) {        // waves 2-3: hsc/hfin stores
            const int k = tid - 128;
            const int row = k >> 3, sl = (k >> 2) & 1, c4 = k & 3;
            const int col = (fg + 16 * sl) * 16 + c4 * 4;
            const int b = bb * 16 + row;
            u32x4 val = *(const u32x4*)&H32L[row][sl * 16 + c4 * 4];
            *(u32x4*)(hsc + ((size_t)b * TT + t) * DH + col) = val;
            if (t == TT - 1) *(u32x4*)(hfin + (size_t)b * DH + col) = val;
        }
    }
}

extern "C" void kernel_launch(void* const* d_in, const int* in_sizes, int n_in,
                              void* d_out, int out_size, void* d_ws, size_t ws_size,
                              hipStream_t stream) {
    const float* X    = (const float*)d_in[0];
    const float* Mm   = (const float*)d_in[1];
    const float* Wih0 = (const float*)d_in[2];
    const float* Whh0 = (const float*)d_in[3];
    const float* bih0 = (const float*)d_in[4];
    const float* bhh0 = (const float*)d_in[5];
    const float* Wih1 = (const float*)d_in[6];
    const float* Whh1 = (const float*)d_in[7];
    const float* bih1 = (const float*)d_in[8];
    const float* bhh1 = (const float*)d_in[9];
    const float* Wout = (const float*)d_in[10];
    const float* bout = (const float*)d_in[11];
    float* out = (float*)d_out;
    float* ws  = (float*)d_ws;

    // zero flags + Hbf (initial hidden state)
    hipMemsetAsync(d_ws, 0, (size_t)(OFF_H1BF) * sizeof(float), stream);

    // weights fp32 -> bf16
    hipLaunchKernelGGL(prep_kernel, dim3(1024), dim3(256), 0, stream,
                       Wout, Whh0, Wih0, Wih1, Whh1, ws);

    // persistent RNN: 256 WGs (<= 256 CUs) x 512 threads, co-resident
    hipLaunchKernelGGL(rnn_kernel, dim3(256), dim3(512), 0, stream,
                       X, Mm, bih0, bhh0, bih1, bhh1, bout, out, ws);
}